// Round 1
// baseline (94.325 us; speedup 1.0000x reference)
//
#include <hip/hip_runtime.h>

constexpr int BB = 32;
constexpr int NN = 1024;
#define PATCH 14.0f
#define THRSQ 25.0f   // PIXEL_THRESHOLD^2 ; sqrt(x)<=5 <=> x<=25 for correctly-rounded sqrt

// ---------------- Kernel 1: score every hypothesis ----------------
// grid = BB * (NN/128) blocks, 128 threads. One hypothesis per thread.
__global__ __launch_bounds__(128) void ransac_score_kernel(
    const float* __restrict__ src, const float* __restrict__ tar,
    const float* __restrict__ scores, const float* __restrict__ relScale,
    const float* __restrict__ relInplane, float* __restrict__ score_inl)
{
#pragma clang fp contract(off)
    const int blocksPerBatch = NN / 128;
    const int b = blockIdx.x / blocksPerBatch;
    const int n = (blockIdx.x % blocksPerBatch) * 128 + threadIdx.x;

    __shared__ float s_x[NN], s_y[NN], t_x[NN], t_y[NN], sc[NN];

    const float* srcb = src + (size_t)b * NN * 2;
    const float* tarb = tar + (size_t)b * NN * 2;
    const float* scb  = scores + (size_t)b * NN;

    for (int i = threadIdx.x; i < NN; i += 128) {
        float sxr = srcb[2 * i];
        float syr = srcb[2 * i + 1];
        s_x[i] = sxr * PATCH;
        s_y[i] = syr * PATCH;
        t_x[i] = tarb[2 * i] * PATCH;
        t_y[i] = tarb[2 * i + 1] * PATCH;
        // invalid m (src.x == -1) can never contribute: zero its score
        sc[i] = (sxr != -1.0f) ? scb[i] : 0.0f;
    }
    __syncthreads();

    const float scale = relScale[(size_t)b * NN + n];
    const float c  = relInplane[((size_t)b * NN + n) * 2];
    const float si = relInplane[((size_t)b * NN + n) * 2 + 1];
    const float a00 = scale * c;
    const float a01 = scale * (-si);
    const float a10 = scale * si;
    const float a11 = scale * c;

    const float snx = s_x[n], sny = s_y[n];
    const float trx = t_x[n] - (a00 * snx + a01 * sny);
    const float trY = t_y[n] - (a10 * snx + a11 * sny);

    float acc = 0.0f;
    for (int m = 0; m < NN; ++m) {
        float px = a00 * s_x[m] + a01 * s_y[m] + trx;
        float py = a10 * s_x[m] + a11 * s_y[m] + trY;
        float dx = px - t_x[m];
        float dy = py - t_y[m];
        float e2 = dx * dx + dy * dy;
        bool inl = (e2 <= THRSQ) && (m != n);
        acc += inl ? sc[m] : 0.0f;
    }

    bool valid_n = (srcb[2 * n] != -1.0f);
    score_inl[(size_t)b * NN + n] = valid_n ? acc : -1.0f;
}

// ---------------- Kernel 2: argmax + M + stable inlier partition ----------------
// grid = BB blocks, 1024 threads (one per point m).
__global__ __launch_bounds__(1024) void ransac_select_kernel(
    const float* __restrict__ src, const float* __restrict__ tar,
    const float* __restrict__ scores, const float* __restrict__ relScale,
    const float* __restrict__ relInplane,
    const float* __restrict__ score_inl, float* __restrict__ out)
{
#pragma clang fp contract(off)
    const int b = blockIdx.x;
    const int tid = threadIdx.x;

    __shared__ float rval[NN];
    __shared__ int   ridx[NN];
    __shared__ float prm[6];       // a00 a01 a10 a11 trx trY
    __shared__ int   bestIdxSh;
    __shared__ int   wcnt[16], wbase[16];
    __shared__ float osx[NN], osy[NN], otx[NN], oty[NN], osc[NN];

    // ---- argmax with first-index tie-break (matches jnp.argmax) ----
    rval[tid] = score_inl[(size_t)b * NN + tid];
    ridx[tid] = tid;
    __syncthreads();
    for (int s = NN / 2; s > 0; s >>= 1) {
        if (tid < s) {
            float v1 = rval[tid],     v2 = rval[tid + s];
            int   i1 = ridx[tid],     i2 = ridx[tid + s];
            if (v2 > v1 || (v2 == v1 && i2 < i1)) { rval[tid] = v2; ridx[tid] = i2; }
        }
        __syncthreads();
    }

    if (tid == 0) {
        int best = ridx[0];
        bestIdxSh = best;
        size_t gi = (size_t)b * NN + best;
        float scale = relScale[gi];
        float c  = relInplane[gi * 2];
        float si = relInplane[gi * 2 + 1];
        float a00 = scale * c;
        float a01 = scale * (-si);
        float a10 = scale * si;
        float a11 = scale * c;
        float snx = src[gi * 2] * PATCH, sny = src[gi * 2 + 1] * PATCH;
        float tnx = tar[gi * 2] * PATCH, tny = tar[gi * 2 + 1] * PATCH;
        float trx = tnx - (a00 * snx + a01 * sny);
        float trY = tny - (a10 * snx + a11 * sny);
        prm[0] = a00; prm[1] = a01; prm[2] = a10; prm[3] = a11; prm[4] = trx; prm[5] = trY;

        float* M = out + (size_t)b * 9;
        M[0] = a00; M[1] = a01; M[2] = trx;
        M[3] = a10; M[4] = a11; M[5] = trY;
        M[6] = 0.0f; M[7] = 0.0f; M[8] = 1.0f;
        out[(size_t)BB * 9 + b] = (rval[0] == 0.0f) ? 1.0f : 0.0f;   // failed
    }
    __syncthreads();

    // ---- recompute inlier flag for this thread's point m = tid ----
    size_t gm = (size_t)b * NN + tid;
    float sxr = src[gm * 2], syr = src[gm * 2 + 1];
    float txr = tar[gm * 2], tyr = tar[gm * 2 + 1];
    float sx = sxr * PATCH, sy = syr * PATCH;
    float tx = txr * PATCH, ty = tyr * PATCH;
    float px = prm[0] * sx + prm[1] * sy + prm[4];
    float py = prm[2] * sx + prm[3] * sy + prm[5];
    float dx = px - tx, dy = py - ty;
    bool flag = (dx * dx + dy * dy <= THRSQ) && (sxr != -1.0f) && (tid != bestIdxSh);

    // ---- stable exclusive prefix of flags (ballot + popcount + wave scan) ----
    unsigned long long mask = __ballot(flag);
    int lane = tid & 63;
    int wave = tid >> 6;
    int posInWave = __popcll(mask & ((1ULL << lane) - 1ULL));
    if (lane == 0) wcnt[wave] = __popcll(mask);
    __syncthreads();
    if (tid < 16) {
        int s = 0;
        for (int i = 0; i < tid; ++i) s += wcnt[i];
        wbase[tid] = s;
    }
    __syncthreads();
    int pos = wbase[wave] + posInWave;

    // ---- stable partition into LDS, then coalesced write ----
    osx[tid] = -1.0f; osy[tid] = -1.0f;
    otx[tid] = -1.0f; oty[tid] = -1.0f;
    osc[tid] = 0.0f;
    __syncthreads();
    if (flag) {
        osx[pos] = sxr; osy[pos] = syr;
        otx[pos] = txr; oty[pos] = tyr;
        osc[pos] = scores[gm];
    }
    __syncthreads();

    const size_t O_SRC = (size_t)BB * 9 + BB;
    const size_t O_TAR = O_SRC + (size_t)BB * NN * 2;
    const size_t O_SC  = O_TAR + (size_t)BB * NN * 2;
    out[O_SRC + gm * 2]     = osx[tid];
    out[O_SRC + gm * 2 + 1] = osy[tid];
    out[O_TAR + gm * 2]     = otx[tid];
    out[O_TAR + gm * 2 + 1] = oty[tid];
    out[O_SC  + gm]         = osc[tid];
}

extern "C" void kernel_launch(void* const* d_in, const int* in_sizes, int n_in,
                              void* d_out, int out_size, void* d_ws, size_t ws_size,
                              hipStream_t stream) {
    const float* src        = (const float*)d_in[0];
    const float* tar        = (const float*)d_in[1];
    const float* scores     = (const float*)d_in[2];
    const float* relScale   = (const float*)d_in[3];
    const float* relInplane = (const float*)d_in[4];
    float* out = (float*)d_out;
    float* score_inl = (float*)d_ws;   // BB*NN floats = 128 KB

    ransac_score_kernel<<<BB * (NN / 128), 128, 0, stream>>>(
        src, tar, scores, relScale, relInplane, score_inl);
    ransac_select_kernel<<<BB, NN, 0, stream>>>(
        src, tar, scores, relScale, relInplane, score_inl, out);
}

// Round 2
// 21.543 us; speedup vs baseline: 4.3785x; 4.3785x over previous
//
#include <hip/hip_runtime.h>

constexpr int BB = 32;
constexpr int NN = 1024;
constexpr int SPLIT = 16;          // waves per block = m-chunks
constexpr int HYP = 128;           // hypotheses per block
#define PATCH 14.0f
#define THRSQ 25.0f   // PIXEL_THRESHOLD^2 ; sqrt(x)<=5 <=> x<=25 for correctly-rounded sqrt

// ---------------- Kernel 1: score every hypothesis ----------------
// grid = BB * (NN/HYP) blocks, 1024 threads = 16 waves.
// wave w handles m-chunk [w*64, (w+1)*64); lane l owns hypotheses l and l+64.
__global__ __launch_bounds__(1024) void ransac_score_kernel(
    const float* __restrict__ src, const float* __restrict__ tar,
    const float* __restrict__ scores, const float* __restrict__ relScale,
    const float* __restrict__ relInplane, float* __restrict__ score_inl)
{
#pragma clang fp contract(off)
    const int blocksPerBatch = NN / HYP;                 // 8
    const int b   = blockIdx.x / blocksPerBatch;
    const int g   = blockIdx.x % blocksPerBatch;
    const int tid = threadIdx.x;
    const int wave = tid >> 6;
    const int lane = tid & 63;

    __shared__ float4 pts[NN];        // (sx, sy, tx, ty) * PATCH
    __shared__ float  sc[NN];         // score, zeroed for invalid points
    __shared__ float  partial[SPLIT][HYP];

    const float* srcb = src + (size_t)b * NN * 2;
    const float* tarb = tar + (size_t)b * NN * 2;
    const float* scb  = scores + (size_t)b * NN;

    for (int i = tid; i < NN; i += 1024) {
        float2 s = ((const float2*)srcb)[i];
        float2 t = ((const float2*)tarb)[i];
        pts[i] = make_float4(s.x * PATCH, s.y * PATCH, t.x * PATCH, t.y * PATCH);
        sc[i]  = (s.x != -1.0f) ? scb[i] : 0.0f;
    }
    __syncthreads();

    // ---- two hypotheses per thread: n0 = g*128+lane, n1 = n0+64 ----
    const int n0l = lane, n1l = lane + 64;
    const size_t base = (size_t)b * NN + (size_t)g * HYP;

    const float sc0v = relScale[base + n0l];
    const float sc1v = relScale[base + n1l];
    const float2 ip0 = ((const float2*)relInplane)[base + n0l];
    const float2 ip1 = ((const float2*)relInplane)[base + n1l];

    const float a00_0 = sc0v * ip0.x, a01_0 = sc0v * (-ip0.y);
    const float a10_0 = sc0v * ip0.y, a11_0 = sc0v * ip0.x;
    const float a00_1 = sc1v * ip1.x, a01_1 = sc1v * (-ip1.y);
    const float a10_1 = sc1v * ip1.y, a11_1 = sc1v * ip1.x;

    const float4 P0 = pts[g * HYP + n0l];
    const float4 P1 = pts[g * HYP + n1l];
    const float trx0 = P0.z - (a00_0 * P0.x + a01_0 * P0.y);
    const float try0 = P0.w - (a10_0 * P0.x + a11_0 * P0.y);
    const float trx1 = P1.z - (a00_1 * P1.x + a01_1 * P1.y);
    const float try1 = P1.w - (a10_1 * P1.x + a11_1 * P1.y);

    float acc0 = 0.0f, acc1 = 0.0f;
    const int mBeg = wave * (NN / SPLIT);                // 64 per wave
#pragma unroll 4
    for (int mm = 0; mm < NN / SPLIT; ++mm) {
        const int m = mBeg + mm;
        const float4 q = pts[m];       // same addr across wave -> LDS broadcast
        const float  w = sc[m];

        float px0 = a00_0 * q.x + a01_0 * q.y + trx0;
        float py0 = a10_0 * q.x + a11_0 * q.y + try0;
        float dx0 = px0 - q.z, dy0 = py0 - q.w;
        float e20 = dx0 * dx0 + dy0 * dy0;
        acc0 += (e20 <= THRSQ) ? w : 0.0f;

        float px1 = a00_1 * q.x + a01_1 * q.y + trx1;
        float py1 = a10_1 * q.x + a11_1 * q.y + try1;
        float dx1 = px1 - q.z, dy1 = py1 - q.w;
        float e21 = dx1 * dx1 + dy1 * dy1;
        acc1 += (e21 <= THRSQ) ? w : 0.0f;
    }
    partial[wave][n0l] = acc0;
    partial[wave][n1l] = acc1;
    __syncthreads();

    // ---- combine partials; remove self-term (its e2 ~ 1e-8 <= 25 always) ----
    if (tid < HYP) {
        float p = 0.0f;
#pragma unroll
        for (int w = 0; w < SPLIT; ++w) p += partial[w][tid];
        p -= sc[g * HYP + tid];                          // not_self correction
        bool valid = (srcb[2 * (g * HYP + tid)] != -1.0f);
        score_inl[base + tid] = valid ? p : -1.0f;
    }
}

// ---------------- Kernel 2: argmax + M + stable inlier partition ----------------
// grid = BB blocks, 1024 threads (one per point m).  (unchanged from passing R1)
__global__ __launch_bounds__(1024) void ransac_select_kernel(
    const float* __restrict__ src, const float* __restrict__ tar,
    const float* __restrict__ scores, const float* __restrict__ relScale,
    const float* __restrict__ relInplane,
    const float* __restrict__ score_inl, float* __restrict__ out)
{
#pragma clang fp contract(off)
    const int b = blockIdx.x;
    const int tid = threadIdx.x;

    __shared__ float rval[NN];
    __shared__ int   ridx[NN];
    __shared__ float prm[6];       // a00 a01 a10 a11 trx trY
    __shared__ int   bestIdxSh;
    __shared__ int   wcnt[16], wbase[16];
    __shared__ float osx[NN], osy[NN], otx[NN], oty[NN], osc[NN];

    // ---- argmax with first-index tie-break (matches jnp.argmax) ----
    rval[tid] = score_inl[(size_t)b * NN + tid];
    ridx[tid] = tid;
    __syncthreads();
    for (int s = NN / 2; s > 0; s >>= 1) {
        if (tid < s) {
            float v1 = rval[tid],     v2 = rval[tid + s];
            int   i1 = ridx[tid],     i2 = ridx[tid + s];
            if (v2 > v1 || (v2 == v1 && i2 < i1)) { rval[tid] = v2; ridx[tid] = i2; }
        }
        __syncthreads();
    }

    if (tid == 0) {
        int best = ridx[0];
        bestIdxSh = best;
        size_t gi = (size_t)b * NN + best;
        float scale = relScale[gi];
        float c  = relInplane[gi * 2];
        float si = relInplane[gi * 2 + 1];
        float a00 = scale * c;
        float a01 = scale * (-si);
        float a10 = scale * si;
        float a11 = scale * c;
        float snx = src[gi * 2] * PATCH, sny = src[gi * 2 + 1] * PATCH;
        float tnx = tar[gi * 2] * PATCH, tny = tar[gi * 2 + 1] * PATCH;
        float trx = tnx - (a00 * snx + a01 * sny);
        float trY = tny - (a10 * snx + a11 * sny);
        prm[0] = a00; prm[1] = a01; prm[2] = a10; prm[3] = a11; prm[4] = trx; prm[5] = trY;

        float* M = out + (size_t)b * 9;
        M[0] = a00; M[1] = a01; M[2] = trx;
        M[3] = a10; M[4] = a11; M[5] = trY;
        M[6] = 0.0f; M[7] = 0.0f; M[8] = 1.0f;
        out[(size_t)BB * 9 + b] = (rval[0] == 0.0f) ? 1.0f : 0.0f;   // failed
    }
    __syncthreads();

    // ---- recompute inlier flag for this thread's point m = tid ----
    size_t gm = (size_t)b * NN + tid;
    float sxr = src[gm * 2], syr = src[gm * 2 + 1];
    float txr = tar[gm * 2], tyr = tar[gm * 2 + 1];
    float sx = sxr * PATCH, sy = syr * PATCH;
    float tx = txr * PATCH, ty = tyr * PATCH;
    float px = prm[0] * sx + prm[1] * sy + prm[4];
    float py = prm[2] * sx + prm[3] * sy + prm[5];
    float dx = px - tx, dy = py - ty;
    bool flag = (dx * dx + dy * dy <= THRSQ) && (sxr != -1.0f) && (tid != bestIdxSh);

    // ---- stable exclusive prefix of flags (ballot + popcount + wave scan) ----
    unsigned long long mask = __ballot(flag);
    int lane = tid & 63;
    int wave = tid >> 6;
    int posInWave = __popcll(mask & ((1ULL << lane) - 1ULL));
    if (lane == 0) wcnt[wave] = __popcll(mask);
    __syncthreads();
    if (tid < 16) {
        int s = 0;
        for (int i = 0; i < tid; ++i) s += wcnt[i];
        wbase[tid] = s;
    }
    __syncthreads();
    int pos = wbase[wave] + posInWave;

    // ---- stable partition into LDS, then coalesced write ----
    osx[tid] = -1.0f; osy[tid] = -1.0f;
    otx[tid] = -1.0f; oty[tid] = -1.0f;
    osc[tid] = 0.0f;
    __syncthreads();
    if (flag) {
        osx[pos] = sxr; osy[pos] = syr;
        otx[pos] = txr; oty[pos] = tyr;
        osc[pos] = scores[gm];
    }
    __syncthreads();

    const size_t O_SRC = (size_t)BB * 9 + BB;
    const size_t O_TAR = O_SRC + (size_t)BB * NN * 2;
    const size_t O_SC  = O_TAR + (size_t)BB * NN * 2;
    out[O_SRC + gm * 2]     = osx[tid];
    out[O_SRC + gm * 2 + 1] = osy[tid];
    out[O_TAR + gm * 2]     = otx[tid];
    out[O_TAR + gm * 2 + 1] = oty[tid];
    out[O_SC  + gm]         = osc[tid];
}

extern "C" void kernel_launch(void* const* d_in, const int* in_sizes, int n_in,
                              void* d_out, int out_size, void* d_ws, size_t ws_size,
                              hipStream_t stream) {
    const float* src        = (const float*)d_in[0];
    const float* tar        = (const float*)d_in[1];
    const float* scores     = (const float*)d_in[2];
    const float* relScale   = (const float*)d_in[3];
    const float* relInplane = (const float*)d_in[4];
    float* out = (float*)d_out;
    float* score_inl = (float*)d_ws;   // BB*NN floats = 128 KB

    ransac_score_kernel<<<BB * (NN / HYP), 1024, 0, stream>>>(
        src, tar, scores, relScale, relInplane, score_inl);
    ransac_select_kernel<<<BB, NN, 0, stream>>>(
        src, tar, scores, relScale, relInplane, score_inl, out);
}